// Round 7
// baseline (5471.259 us; speedup 1.0000x reference)
//
#include <hip/hip_runtime.h>
#include <math.h>

typedef __bf16 bf16;
typedef __attribute__((ext_vector_type(8))) __bf16 bf16x8;
typedef __attribute__((ext_vector_type(4))) float f32x4;

constexpr int TT = 32, BB = 256, HH = 384, GG = 1536;
constexpr float LN_EPS = 1e-5f;
constexpr int NBLK = 24;  // scan grid: 24 blocks x 256 thr

__device__ __forceinline__ float sigm(float x) { return 1.0f / (1.0f + __expf(-x)); }

// split fp32 into 3 bf16 planes: x = h + m + l + O(2^-27 x)
__device__ __forceinline__ void split3(float x, bf16& h, bf16& m, bf16& l) {
    h = (bf16)x; float r = x - (float)h;
    m = (bf16)r; float r2 = r - (float)m;
    l = (bf16)r2;
}

// ---------------------------------------------------------------------------
// device-scope grid barrier (24 co-resident blocks; generation counter in ws)
// ---------------------------------------------------------------------------
__device__ __forceinline__ void grid_sync(unsigned* bar) {
    __syncthreads();
    if (threadIdx.x == 0) {
        __threadfence();
        unsigned g = __hip_atomic_load(bar + 1, __ATOMIC_RELAXED, __HIP_MEMORY_SCOPE_AGENT);
        unsigned old = __hip_atomic_fetch_add(bar + 0, 1u, __ATOMIC_ACQ_REL, __HIP_MEMORY_SCOPE_AGENT);
        if (old == NBLK - 1) {
            __hip_atomic_store(bar + 0, 0u, __ATOMIC_RELAXED, __HIP_MEMORY_SCOPE_AGENT);
            __hip_atomic_fetch_add(bar + 1, 1u, __ATOMIC_ACQ_REL, __HIP_MEMORY_SCOPE_AGENT);
        } else {
            while (__hip_atomic_load(bar + 1, __ATOMIC_ACQUIRE, __HIP_MEMORY_SCOPE_AGENT) == g)
                __builtin_amdgcn_s_sleep(2);
        }
        __threadfence();
    }
    __syncthreads();
}

__global__ void init_bar(unsigned* bar) { bar[0] = 0; bar[1] = 0; }

// ---------------------------------------------------------------------------
// transpose + fp32 -> 3 bf16 planes: in[K][N] -> out[plane][n'][K].
// PERM: n' = gate-interleaved ((r>>4)*4+p)*16+(r&15) for n = p*384 + r.
// ---------------------------------------------------------------------------
template<bool PERM>
__global__ __launch_bounds__(256)
void transpose_cvt3(const float* __restrict__ in, bf16* __restrict__ out,
                    int K, int N)
{
    __shared__ float tile[32][33];
    const int k0 = blockIdx.y * 32;
    const int n0 = blockIdx.x * 32;
    const int tx = threadIdx.x & 31;
    const int ty = threadIdx.x >> 5;  // 0..7
    const size_t PS = (size_t)N * K;
    #pragma unroll
    for (int i = 0; i < 4; ++i)
        tile[ty + i * 8][tx] = in[(long)(k0 + ty + i * 8) * N + n0 + tx];
    __syncthreads();
    #pragma unroll
    for (int i = 0; i < 4; ++i) {
        const int n = n0 + ty + i * 8;
        int orow;
        if (PERM) {
            const int p = n / HH, r = n - p * HH;
            orow = ((r >> 4) * 4 + p) * 16 + (r & 15);
        } else orow = n;
        bf16 h, m, l;
        split3(tile[tx][ty + i * 8], h, m, l);
        const size_t base = (size_t)orow * K + k0 + tx;
        out[base] = h; out[PS + base] = m; out[2 * PS + base] = l;
    }
}

// ---------------------------------------------------------------------------
// Split-precision MFMA GEMM: C[M,N] = A[M,K] @ Bt[N,K]^T, fp32 in/out.
// A fp32, split to 3 bf16 planes in-kernel; B pre-split (Bt3 = [3][N][K]).
// 6 MFMA terms (i+j<=2) -> fp32-equivalent product error ~2^-25.
// 128x128 tile, BK=32, 256 thr (2x2 waves, 4x4 16x16x32 frags each).
// ---------------------------------------------------------------------------
template<bool CONCAT>
__global__ __launch_bounds__(256)
void gemm_proj(const float* __restrict__ A,
               const float* __restrict__ Aent, const float* __restrict__ Aspa,
               const float* __restrict__ Asca,
               const bf16* __restrict__ Bt3, float* __restrict__ C,
               int K, int N)
{
    constexpr int LDA = 40;  // 32 + 8 pad (80B rows, 16B aligned)
    __shared__ bf16 As[3][128 * LDA];
    __shared__ bf16 Bs[3][128 * LDA];
    const int tid = threadIdx.x;
    const long bm = (long)blockIdx.y * 128;
    const int bn = blockIdx.x * 128;
    const int srow = tid & 127;
    const int soff = (tid >> 7) * 16;   // 0 or 16 (elems)
    const int lane = tid & 63;
    const int wid  = tid >> 6;
    const int wm = (wid >> 1) * 64, wn = (wid & 1) * 64;
    const int cc = lane & 15, g = lane >> 4;
    const size_t PS = (size_t)N * K;

    const f32x4 zero = {0.f, 0.f, 0.f, 0.f};
    f32x4 acc[4][4];
    #pragma unroll
    for (int m = 0; m < 4; ++m)
        #pragma unroll
        for (int n = 0; n < 4; ++n) acc[m][n] = zero;

    for (int k0 = 0; k0 < K; k0 += 32) {
        float va[16];
        if (!CONCAT) {
            const float* p = A + (bm + srow) * (long)K + k0 + soff;
            #pragma unroll
            for (int i = 0; i < 4; ++i) {
                const float4 v = *(const float4*)(p + i * 4);
                va[i*4+0] = v.x; va[i*4+1] = v.y; va[i*4+2] = v.z; va[i*4+3] = v.w;
            }
        } else {
            const int acol = k0 + soff;  // multiple of 16; segments at 256/512 ok
            const float* p;
            if (acol < 256)      p = Aent + (bm + srow) * 256 + acol;
            else if (acol < 512) p = Aspa + (bm + srow) * 256 + (acol - 256);
            else                 p = Asca + (bm + srow) * 640 + (acol - 512);
            #pragma unroll
            for (int i = 0; i < 4; ++i) {
                const float4 v = *(const float4*)(p + i * 4);
                va[i*4+0] = v.x; va[i*4+1] = v.y; va[i*4+2] = v.z; va[i*4+3] = v.w;
            }
        }
        bf16 ah[16], am[16], al[16];
        #pragma unroll
        for (int e = 0; e < 16; ++e) split3(va[e], ah[e], am[e], al[e]);
        const bf16* bp = Bt3 + (bn + srow) * (long)K + k0 + soff;
        const bf16x8 b00 = *(const bf16x8*)bp;
        const bf16x8 b01 = *(const bf16x8*)(bp + 8);
        const bf16x8 b10 = *(const bf16x8*)(bp + PS);
        const bf16x8 b11 = *(const bf16x8*)(bp + PS + 8);
        const bf16x8 b20 = *(const bf16x8*)(bp + 2 * PS);
        const bf16x8 b21 = *(const bf16x8*)(bp + 2 * PS + 8);
        __syncthreads();  // previous tile's reads done
        *(bf16x8*)&As[0][srow * LDA + soff]     = *(bf16x8*)&ah[0];
        *(bf16x8*)&As[0][srow * LDA + soff + 8] = *(bf16x8*)&ah[8];
        *(bf16x8*)&As[1][srow * LDA + soff]     = *(bf16x8*)&am[0];
        *(bf16x8*)&As[1][srow * LDA + soff + 8] = *(bf16x8*)&am[8];
        *(bf16x8*)&As[2][srow * LDA + soff]     = *(bf16x8*)&al[0];
        *(bf16x8*)&As[2][srow * LDA + soff + 8] = *(bf16x8*)&al[8];
        *(bf16x8*)&Bs[0][srow * LDA + soff]     = b00;
        *(bf16x8*)&Bs[0][srow * LDA + soff + 8] = b01;
        *(bf16x8*)&Bs[1][srow * LDA + soff]     = b10;
        *(bf16x8*)&Bs[1][srow * LDA + soff + 8] = b11;
        *(bf16x8*)&Bs[2][srow * LDA + soff]     = b20;
        *(bf16x8*)&Bs[2][srow * LDA + soff + 8] = b21;
        __syncthreads();
        bf16x8 a0[4], a1[4], a2[4], bb[4];
        #pragma unroll
        for (int m = 0; m < 4; ++m) {
            const int off = (wm + m * 16 + cc) * LDA + g * 8;
            a0[m] = *(const bf16x8*)&As[0][off];
            a1[m] = *(const bf16x8*)&As[1][off];
            a2[m] = *(const bf16x8*)&As[2][off];
        }
        // j = 0 (B hi): i = 0,1,2
        #pragma unroll
        for (int n = 0; n < 4; ++n)
            bb[n] = *(const bf16x8*)&Bs[0][(wn + n * 16 + cc) * LDA + g * 8];
        #pragma unroll
        for (int m = 0; m < 4; ++m)
            #pragma unroll
            for (int n = 0; n < 4; ++n) {
                acc[m][n] = __builtin_amdgcn_mfma_f32_16x16x32_bf16(a0[m], bb[n], acc[m][n], 0, 0, 0);
                acc[m][n] = __builtin_amdgcn_mfma_f32_16x16x32_bf16(a1[m], bb[n], acc[m][n], 0, 0, 0);
                acc[m][n] = __builtin_amdgcn_mfma_f32_16x16x32_bf16(a2[m], bb[n], acc[m][n], 0, 0, 0);
            }
        // j = 1 (B mid): i = 0,1
        #pragma unroll
        for (int n = 0; n < 4; ++n)
            bb[n] = *(const bf16x8*)&Bs[1][(wn + n * 16 + cc) * LDA + g * 8];
        #pragma unroll
        for (int m = 0; m < 4; ++m)
            #pragma unroll
            for (int n = 0; n < 4; ++n) {
                acc[m][n] = __builtin_amdgcn_mfma_f32_16x16x32_bf16(a0[m], bb[n], acc[m][n], 0, 0, 0);
                acc[m][n] = __builtin_amdgcn_mfma_f32_16x16x32_bf16(a1[m], bb[n], acc[m][n], 0, 0, 0);
            }
        // j = 2 (B lo): i = 0
        #pragma unroll
        for (int n = 0; n < 4; ++n)
            bb[n] = *(const bf16x8*)&Bs[2][(wn + n * 16 + cc) * LDA + g * 8];
        #pragma unroll
        for (int m = 0; m < 4; ++m)
            #pragma unroll
            for (int n = 0; n < 4; ++n)
                acc[m][n] = __builtin_amdgcn_mfma_f32_16x16x32_bf16(a0[m], bb[n], acc[m][n], 0, 0, 0);
    }
    #pragma unroll
    for (int m = 0; m < 4; ++m) {
        const long row0 = bm + wm + m * 16 + g * 4;
        #pragma unroll
        for (int n = 0; n < 4; ++n) {
            const int col = bn + wn + n * 16 + cc;
            #pragma unroll
            for (int r = 0; r < 4; ++r)
                C[(row0 + r) * (long)N + col] = acc[m][n][r];
        }
    }
}

// ---------------------------------------------------------------------------
// Row LayerNorm over 1536, in place (round-1 verified).
// ---------------------------------------------------------------------------
__global__ __launch_bounds__(256)
void ln_rows(float* __restrict__ X, const float* __restrict__ g,
             const float* __restrict__ b)
{
    float* x = X + (long)blockIdx.x * GG;
    const int tid = threadIdx.x;
    float v[6];
    float s = 0.f, q = 0.f;
    #pragma unroll
    for (int i = 0; i < 6; ++i) {
        v[i] = x[tid + i * 256];
        s += v[i]; q += v[i] * v[i];
    }
    #pragma unroll
    for (int o = 32; o; o >>= 1) { s += __shfl_xor(s, o); q += __shfl_xor(q, o); }
    __shared__ float red[2][4];
    const int wave = tid >> 6;
    if ((tid & 63) == 0) { red[0][wave] = s; red[1][wave] = q; }
    __syncthreads();
    float S = 0.f, Q = 0.f;
    #pragma unroll
    for (int w = 0; w < 4; ++w) { S += red[0][w]; Q += red[1][w]; }
    const float mean = S * (1.0f / GG);
    const float var  = Q * (1.0f / GG) - mean * mean;
    const float rs   = rsqrtf(var + LN_EPS);
    #pragma unroll
    for (int i = 0; i < 6; ++i) {
        const int col = tid + i * 256;
        x[col] = (v[i] - mean) * rs * g[col] + b[col];
    }
}

// ---------------------------------------------------------------------------
// Persistent fused LSTM scan, split-precision recurrent GEMM.
// Grid: 24 blocks (ni = gate-col tile) x 256 thr (4 waves = row tiles mi).
// h kept fp32 in the cell; re-split to 3 bf16 planes (hp) each step.
// ---------------------------------------------------------------------------
__device__ __forceinline__ float red16(float v) {
    v += __shfl_xor(v, 1); v += __shfl_xor(v, 2);
    v += __shfl_xor(v, 4); v += __shfl_xor(v, 8);
    return v;
}

__global__ __launch_bounds__(256)
void lstm_scan(const bf16* __restrict__ whT3,    // [3][1536][384] gate-permuted
               const float* __restrict__ xg,     // [T*B][1536], LN'd
               const float* __restrict__ bias_l,
               const float* __restrict__ ghw_l,
               const float* __restrict__ ghb_l,
               const float* __restrict__ h0_l,
               const float* __restrict__ c0_l,
               bf16*  __restrict__ hp,           // [3][256][384] h planes
               float* __restrict__ c_state,      // [256][384]
               float* __restrict__ partials,     // [24][256][2]
               unsigned* __restrict__ bar,
               float* __restrict__ xout,         // [T,B,H] fp32 (next input / final)
               float* __restrict__ hn, float* __restrict__ cn)
{
    constexpr int LDB = 392;  // 384 + 8 pad (784B rows, 16B aligned)
    __shared__ bf16 Bsh[3][64 * LDB];    // 150.5 KB: 64 gate cols x 384 k x 3 planes
    __shared__ float stats[BB][2];

    const int tid = threadIdx.x;
    const int ni = blockIdx.x;
    const int mi = tid >> 6;
    const int lane = tid & 63;
    const int cc = lane & 15, g = lane >> 4;
    const size_t SB = (size_t)BB * HH;
    const size_t WP = (size_t)GG * HH;

    // init recurrent state (fp32 h0 split to planes)
    for (int i = ni * 256 + tid; i < BB * HH; i += NBLK * 256) {
        bf16 h, m, l; split3(h0_l[i], h, m, l);
        hp[i] = h; hp[SB + i] = m; hp[2 * SB + i] = l;
        c_state[i] = c0_l[i];
    }
    // stage whT3 rows [ni*64, ni*64+64), all 3 planes (t-invariant)
    #pragma unroll
    for (int q = 0; q < 3; ++q) {
        const bf16* src = whT3 + q * WP + (size_t)ni * 64 * HH;
        for (int cid = tid; cid < 64 * 48; cid += 256) {
            const int rl = cid / 48, kc = (cid % 48) * 8;
            *(bf16x8*)&Bsh[q][rl * LDB + kc] = *(const bf16x8*)(src + rl * HH + kc);
        }
    }
    float gw[4], gc[4];
    #pragma unroll
    for (int p = 0; p < 4; ++p) {
        const int col = p * HH + ni * 16 + cc;
        gw[p] = ghw_l[col];
        gc[p] = ghb_l[col] + bias_l[col];
    }
    grid_sync(bar);

    const f32x4 zero = {0.f, 0.f, 0.f, 0.f};
    for (int t = 0; t < TT; ++t) {
        // ---- split-precision GEMM: h @ wh for this block's 64 gate cols
        f32x4 acc[4][4];
        #pragma unroll
        for (int m = 0; m < 4; ++m)
            #pragma unroll
            for (int p = 0; p < 4; ++p) acc[m][p] = zero;
        for (int ks = 0; ks < 12; ++ks) {
            const int k = ks * 32 + g * 8;
            bf16x8 a0[4], a1[4], a2[4], bb[4];
            #pragma unroll
            for (int m = 0; m < 4; ++m) {
                const size_t off = (size_t)(mi * 64 + m * 16 + cc) * HH + k;
                a0[m] = *(const bf16x8*)(hp + off);
                a1[m] = *(const bf16x8*)(hp + SB + off);
                a2[m] = *(const bf16x8*)(hp + 2 * SB + off);
            }
            #pragma unroll
            for (int p = 0; p < 4; ++p)
                bb[p] = *(const bf16x8*)&Bsh[0][(p * 16 + cc) * LDB + k];
            #pragma unroll
            for (int m = 0; m < 4; ++m)
                #pragma unroll
                for (int p = 0; p < 4; ++p) {
                    acc[m][p] = __builtin_amdgcn_mfma_f32_16x16x32_bf16(a0[m], bb[p], acc[m][p], 0, 0, 0);
                    acc[m][p] = __builtin_amdgcn_mfma_f32_16x16x32_bf16(a1[m], bb[p], acc[m][p], 0, 0, 0);
                    acc[m][p] = __builtin_amdgcn_mfma_f32_16x16x32_bf16(a2[m], bb[p], acc[m][p], 0, 0, 0);
                }
            #pragma unroll
            for (int p = 0; p < 4; ++p)
                bb[p] = *(const bf16x8*)&Bsh[1][(p * 16 + cc) * LDB + k];
            #pragma unroll
            for (int m = 0; m < 4; ++m)
                #pragma unroll
                for (int p = 0; p < 4; ++p) {
                    acc[m][p] = __builtin_amdgcn_mfma_f32_16x16x32_bf16(a0[m], bb[p], acc[m][p], 0, 0, 0);
                    acc[m][p] = __builtin_amdgcn_mfma_f32_16x16x32_bf16(a1[m], bb[p], acc[m][p], 0, 0, 0);
                }
            #pragma unroll
            for (int p = 0; p < 4; ++p)
                bb[p] = *(const bf16x8*)&Bsh[2][(p * 16 + cc) * LDB + k];
            #pragma unroll
            for (int m = 0; m < 4; ++m)
                #pragma unroll
                for (int p = 0; p < 4; ++p)
                    acc[m][p] = __builtin_amdgcn_mfma_f32_16x16x32_bf16(a0[m], bb[p], acc[m][p], 0, 0, 0);
        }
        // ---- LN partial sums over this tile's 64 cols, per row
        #pragma unroll
        for (int m = 0; m < 4; ++m) {
            float s[4], q[4];
            #pragma unroll
            for (int r = 0; r < 4; ++r) { s[r] = 0.f; q[r] = 0.f; }
            #pragma unroll
            for (int p = 0; p < 4; ++p)
                #pragma unroll
                for (int r = 0; r < 4; ++r) {
                    const float v = acc[m][p][r];
                    s[r] += v; q[r] += v * v;
                }
            #pragma unroll
            for (int r = 0; r < 4; ++r) { s[r] = red16(s[r]); q[r] = red16(q[r]); }
            if (cc == 0) {
                #pragma unroll
                for (int r = 0; r < 4; ++r) {
                    const int row = mi * 64 + m * 16 + g * 4 + r;
                    partials[(ni * BB + row) * 2 + 0] = s[r];
                    partials[(ni * BB + row) * 2 + 1] = q[r];
                }
            }
        }
        grid_sync(bar);
        // ---- full-row stats (each thread owns one of 256 rows)
        {
            float S = 0.f, Q = 0.f;
            #pragma unroll
            for (int n2 = 0; n2 < NBLK; ++n2) {
                S += partials[(n2 * BB + tid) * 2 + 0];
                Q += partials[(n2 * BB + tid) * 2 + 1];
            }
            const float mean = S * (1.0f / GG);
            const float var  = Q * (1.0f / GG) - mean * mean;
            stats[tid][0] = mean;
            stats[tid][1] = rsqrtf(var + LN_EPS);
        }
        __syncthreads();
        // ---- cell: all 4 gates of hidden j in-lane; h fp32, re-split
        const float* xgt = xg + (long)t * BB * GG;
        const int j = ni * 16 + cc;
        #pragma unroll
        for (int m = 0; m < 4; ++m) {
            #pragma unroll
            for (int r = 0; r < 4; ++r) {
                const int b = mi * 64 + m * 16 + g * 4 + r;
                const float mean = stats[b][0], rs = stats[b][1];
                float gate[4];
                #pragma unroll
                for (int p = 0; p < 4; ++p) {
                    const int col = p * HH + ni * 16 + cc;
                    gate[p] = (acc[m][p][r] - mean) * rs * gw[p] + gc[p]
                              + xgt[(long)b * GG + col];
                }
                const int idx = b * HH + j;
                const float cprev = c_state[idx];
                const float cnew  = sigm(gate[1]) * cprev + sigm(gate[0]) * tanhf(gate[3]);
                const float h     = sigm(gate[2]) * tanhf(cnew);
                c_state[idx] = cnew;
                bf16 hh, hm, hl; split3(h, hh, hm, hl);
                hp[idx] = hh; hp[SB + idx] = hm; hp[2 * SB + idx] = hl;
                xout[((long)t * BB + b) * HH + j] = h;
                if (t == TT - 1) { hn[idx] = h; cn[idx] = cnew; }
            }
        }
        grid_sync(bar);
    }
}

// ---------------------------------------------------------------------------
extern "C" void kernel_launch(void* const* d_in, const int* in_sizes, int n_in,
                              void* d_out, int out_size, void* d_ws, size_t ws_size,
                              hipStream_t stream)
{
    const float* ent  = (const float*)d_in[0];
    const float* spa  = (const float*)d_in[1];
    const float* sca  = (const float*)d_in[2];
    const float* h0   = (const float*)d_in[3];
    const float* c0   = (const float*)d_in[4];
    const float* wx[3] = { (const float*)d_in[5], (const float*)d_in[6], (const float*)d_in[7] };
    const float* wh   = (const float*)d_in[8];
    const float* bias = (const float*)d_in[9];
    const float* gxw  = (const float*)d_in[10];
    const float* gxb  = (const float*)d_in[11];
    const float* ghw  = (const float*)d_in[12];
    const float* ghb  = (const float*)d_in[13];

    float* out    = (float*)d_out;
    float* out_x  = out;
    float* out_hn = out + (long)TT * BB * HH;
    float* out_cn = out_hn + 3L * BB * HH;

    char* w = (char*)d_ws;
    float* xg      = (float*)w;  w += (size_t)TT * BB * GG * 4;        // 50.3 MB
    bf16*  wxT3    = (bf16*)w;   w += (size_t)3 * GG * 1152 * 2;       // 10.6 MB
    bf16*  whT3    = (bf16*)w;   w += (size_t)3 * GG * HH * 2;         // 3.5 MB
    float* xf      = (float*)w;  w += (size_t)TT * BB * HH * 4;        // 12.6 MB (inter-layer, reused)
    bf16*  hp      = (bf16*)w;   w += (size_t)3 * BB * HH * 2;         // 0.59 MB
    float* c_state = (float*)w;  w += (size_t)BB * HH * 4;             // 0.39 MB
    float* parts   = (float*)w;  w += (size_t)NBLK * BB * 2 * 4;       // 49 KB
    unsigned* bar  = (unsigned*)w;

    init_bar<<<1, 1, 0, stream>>>(bar);

    const int M = TT * BB;  // 8192
    for (int l = 0; l < 3; ++l) {
        const int K = (l == 0) ? 1152 : HH;
        transpose_cvt3<false><<<dim3(GG / 32, K / 32), 256, 0, stream>>>(wx[l], wxT3, K, GG);
        transpose_cvt3<true ><<<dim3(GG / 32, HH / 32), 256, 0, stream>>>(wh + (long)l * HH * GG, whT3, HH, GG);

        dim3 pgrid(GG / 128, M / 128);
        if (l == 0)
            gemm_proj<true ><<<pgrid, 256, 0, stream>>>(nullptr, ent, spa, sca, wxT3, xg, K, GG);
        else
            gemm_proj<false><<<pgrid, 256, 0, stream>>>(xf, nullptr, nullptr, nullptr, wxT3, xg, K, GG);
        ln_rows<<<M, 256, 0, stream>>>(xg, gxw + l * GG, gxb + l * GG);

        lstm_scan<<<NBLK, 256, 0, stream>>>(whT3, xg,
            bias + l * GG, ghw + l * GG, ghb + l * GG,
            h0 + (long)l * BB * HH, c0 + (long)l * BB * HH,
            hp, c_state, parts, bar,
            (l == 2) ? out_x : xf,
            out_hn + (long)l * BB * HH, out_cn + (long)l * BB * HH);
    }
    (void)in_sizes; (void)n_in; (void)out_size; (void)ws_size;
}